// Round 25
// baseline (790.675 us; speedup 1.0000x reference)
//
#include <hip/hip_runtime.h>

// Soft-DTW, gamma=1.0, B=64, N=M=1024. Linear-weight cells + integer-exponent
// scale tracking (R15-R20 numerics, proven absmax 0.0).
// R25 = R20 kernel body VERBATIM; grid reshaped for SIMD co-residency:
// 16 blocks x 512 threads (8 waves). Wave w of block blk runs panel-job
// blk*8+w (batch job>>1, panel job&1) -> 2 waves per SIMD. Rationale: all
// rounds fit "wall = iters x instr x ~4.5cyc" (1-wave dependent-issue
// latency; R23 proved memory/trans irrelevant). A 2nd co-resident wave per
// SIMD (m114 mechanism) interleaves instructions toward the 2cyc issue rate.
// Global poison mailbox + 8-deep static prefetch ring unchanged; s_sleep(1)
// in spins so fill-phase consumers don't burn their SIMD partner's slots.

#define LOG2E 1.4426950408889634f
#define LN2  0.6931471805599453f

constexpr int N = 1024;
constexpr int TPB = 512;             // 8 waves = 8 panel-jobs per block
constexpr int KC = 8;                // columns per thread (panel = 512 cols)
constexpr int RQ = 4;                // rows per iteration (quad)
constexpr int NQ = N / RQ;           // 256 quads
constexpr int NPAN = 2;
constexpr int PC = N / NPAN;         // 512 columns per panel
constexpr int ITER = 320;            // last real iteration: 255 + 63 = 318
constexpr unsigned long long POISON = 0xFFFFFFFFFFFFFFFFull;

__device__ __forceinline__ float fexp2(float x){float r;asm("v_exp_f32 %0, %1":"=v"(r):"v"(x));return r;}
__device__ __forceinline__ float flog2(float x){float r;asm("v_log_f32 %0, %1":"=v"(r):"v"(x));return r;}
__device__ __forceinline__ int   ffrexpe(float x){int r;asm("v_frexp_exp_i32_f32 %0, %1":"=v"(r):"v"(x));return r;}
__device__ __forceinline__ float fldexp(float x, int e){float r;asm("v_ldexp_f32 %0, %1, %2":"=v"(r):"v"(x),"v"(e));return r;}
__device__ __forceinline__ unsigned long long packv(float a, float b){
    return ((unsigned long long)__float_as_uint(b) << 32) | __float_as_uint(a);
}
__device__ __forceinline__ unsigned long long ldrelax(const unsigned long long* p){
    return __hip_atomic_load(p, __ATOMIC_RELAXED, __HIP_MEMORY_SCOPE_AGENT);
}

__global__ __launch_bounds__(TPB, 2)
void softdtw_kernel(const float* __restrict__ D, float* __restrict__ out,
                    unsigned long long* __restrict__ pay){
    const int w   = threadIdx.x >> 6;    // wave within block
    const int job = blockIdx.x * 8 + w;  // 0..127
    const int b = job >> 1;              // batch
    const int q = job & 1;               // panel (0 or 1)
    const int t = threadIdx.x & 63;      // lane within wave
    const float* __restrict__ bp = D + (size_t)b * N * N + q * PC + t * KC;

    const bool isProd = (t == 63) && (q == 0);
    const bool isCons = (t == 0) && (q == 1);
    const size_t base = (size_t)b * NQ * 2;   // one boundary per batch

    float pW[KC] = {0,0,0,0,0,0,0,0};
    int   S = 0;                          // scale: W_true = W * 2^S
    float luW = (t == 0 && q == 0) ? 1.0f : 0.0f;
    float exW[RQ] = {0,0,0,0};
    int   exS = 0;
    float nW[RQ] = {0,0,0,0};
    int   nS = 0;

    // consumer prefetch ring: quad j served from slot j&7 (static indexing)
    unsigned long long rg[8][2];
#pragma unroll
    for (int i = 0; i < 8; ++i) { rg[i][0] = POISON; rg[i][1] = POISON; }
    if (isCons) {
#pragma unroll
        for (int i = 0; i < 8; ++i) {
            rg[i][0] = ldrelax(&pay[base + (size_t)i * 2 + 0]);
            rg[i][1] = ldrelax(&pay[base + (size_t)i * 2 + 1]);
        }
    }

    float4 ld[2][RQ][2];                 // D ring: [slot][row][half], plain loads
#pragma unroll
    for (int x = 0; x < 2; ++x) {
        int pc = min(max(x - t, 0), NQ - 1);
        const float* a = bp + (size_t)(pc * RQ) * N;
#pragma unroll
        for (int r = 0; r < RQ; ++r) {
            ld[x][r][0] = *(const float4*)(a + (size_t)r * N);
            ld[x][r][1] = *(const float4*)(a + (size_t)r * N + 4);
        }
    }
    __builtin_amdgcn_sched_barrier(0);

    for (int jb = 0; jb < ITER; jb += 8) {
#pragma unroll
        for (int u = 0; u < 8; ++u) {
            const int p = jb + u - t;
            const bool active = (unsigned)p < (unsigned)NQ;
            const int slot = u & 1;

            // ---- consumer: validate + decode quad p (t=0 so p==jb+u, slot u) ----
            float cv0 = 0, cv1 = 0, cv2 = 0, cv3 = 0;
            if (isCons && active) {
                unsigned long long w0 = rg[u][0];
                unsigned long long w1 = rg[u][1];
                while (w0 == POISON) {
                    __builtin_amdgcn_s_sleep(1);
                    w0 = ldrelax(&pay[base + (size_t)p * 2 + 0]);
                }
                while (w1 == POISON) {
                    __builtin_amdgcn_s_sleep(1);
                    w1 = ldrelax(&pay[base + (size_t)p * 2 + 1]);
                }
                cv0 = __uint_as_float((unsigned)(w0 & 0xFFFFFFFFu));
                cv1 = __uint_as_float((unsigned)(w0 >> 32));
                cv2 = __uint_as_float((unsigned)(w1 & 0xFFFFFFFFu));
                cv3 = __uint_as_float((unsigned)(w1 >> 32));
            }

            // ---- anchor my scale at my first quad ----
            const int iS = nS;
            if (p == 0) {
                if (isCons) S = (int)(0.0f - cv0);
                else if (t == 0 && q == 0) S = 0;
                else S = iS;
            }

            // ---- incoming left edges in my scale ----
            float eW[RQ];
            {
                const int dS = iS - S;
                eW[0] = fldexp(nW[0], dS); eW[1] = fldexp(nW[1], dS);
                eW[2] = fldexp(nW[2], dS); eW[3] = fldexp(nW[3], dS);
            }
            if (t == 0 && q == 0) { eW[0] = eW[1] = eW[2] = eW[3] = 0.0f; }
            if (isCons) {
                const float Sf = (float)S;
                eW[0] = fexp2(0.0f - cv0 - Sf);
                eW[1] = fexp2(0.0f - cv1 - Sf);
                eW[2] = fexp2(0.0f - cv2 - Sf);
                eW[3] = fexp2(0.0f - cv3 - Sf);
            }

            // ---- 32 cells: W = f*(up + diag + left), 8-wide rows ----
            float a0 = pW[0], a1 = pW[1], a2 = pW[2], a3 = pW[3];
            float a4 = pW[4], a5 = pW[5], a6 = pW[6], a7 = pW[7];
            float dg = luW;
            float eR[RQ];
#pragma unroll
            for (int r = 0; r < RQ; ++r) {
                const float4 d0 = ld[slot][r][0];
                const float4 d1 = ld[slot][r][1];
                float f0 = fexp2(-LOG2E * d0.x), f1 = fexp2(-LOG2E * d0.y);
                float f2 = fexp2(-LOG2E * d0.z), f3 = fexp2(-LOG2E * d0.w);
                float f4 = fexp2(-LOG2E * d1.x), f5 = fexp2(-LOG2E * d1.y);
                float f6 = fexp2(-LOG2E * d1.z), f7 = fexp2(-LOG2E * d1.w);
                float s01 = a0 + a1, s12 = a1 + a2, s23 = a2 + a3, s34 = a3 + a4;
                float s45 = a4 + a5, s56 = a5 + a6, s67 = a6 + a7;
                float t0 = dg + eW[r];
                float W0 = f0 * (a0 + t0);
                float W1 = f1 * (s01 + W0);
                float W2 = f2 * (s12 + W1);
                float W3 = f3 * (s23 + W2);
                float W4 = f4 * (s34 + W3);
                float W5 = f5 * (s45 + W4);
                float W6 = f6 * (s56 + W5);
                float W7 = f7 * (s67 + W6);
                eR[r] = W7;
                dg = eW[r];
                a0 = W0; a1 = W1; a2 = W2; a3 = W3;
                a4 = W4; a5 = W5; a6 = W6; a7 = W7;
            }

            const int e = ffrexpe(a7);
            const float sc = fldexp(1.0f, -e);

            if (active) {                  // masked commit
                pW[0] = a0 * sc; pW[1] = a1 * sc; pW[2] = a2 * sc; pW[3] = a3 * sc;
                pW[4] = a4 * sc; pW[5] = a5 * sc; pW[6] = a6 * sc; pW[7] = a7 * sc;
                luW = dg * sc;
                exW[0] = eR[0] * sc; exW[1] = eR[1] * sc;
                exW[2] = eR[2] * sc; exW[3] = eR[3] * sc;
                S += e; exS = S;
            }

            // ---- producer: publish quad p (normalized v-form, relaxed u64) ----
            if (isProd && active) {
                const float Sf = (float)S;
                float v0 = 0.0f - (flog2(exW[0]) + Sf);
                float v1 = 0.0f - (flog2(exW[1]) + Sf);
                float v2 = 0.0f - (flog2(exW[2]) + Sf);
                float v3 = 0.0f - (flog2(exW[3]) + Sf);
                __hip_atomic_store(&pay[base + (size_t)p * 2 + 0], packv(v0, v1), __ATOMIC_RELAXED, __HIP_MEMORY_SCOPE_AGENT);
                __hip_atomic_store(&pay[base + (size_t)p * 2 + 1], packv(v2, v3), __ATOMIC_RELAXED, __HIP_MEMORY_SCOPE_AGENT);
            }

            // ---- D loads for iteration j+2 into the consumed slot ----
            {
                int pc = min(max(p + 2, 0), NQ - 1);
                const float* a = bp + (size_t)(pc * RQ) * N;
#pragma unroll
                for (int r = 0; r < RQ; ++r) {
                    ld[slot][r][0] = *(const float4*)(a + (size_t)r * N);
                    ld[slot][r][1] = *(const float4*)(a + (size_t)r * N + 4);
                }
            }
            __builtin_amdgcn_sched_barrier(0);

            // ---- consumer: prefetch quad p+8 into ring slot u (used at j+8) ----
            if (isCons && (p + 8) < NQ) {
                rg[u][0] = ldrelax(&pay[base + (size_t)(p + 8) * 2 + 0]);
                rg[u][1] = ldrelax(&pay[base + (size_t)(p + 8) * 2 + 1]);
            }

            // ---- pipelined intra-wave handoff ----
            nW[0] = __shfl_up(exW[0], 1);
            nW[1] = __shfl_up(exW[1], 1);
            nW[2] = __shfl_up(exW[2], 1);
            nW[3] = __shfl_up(exW[3], 1);
            nS    = __shfl_up(exS, 1);
        }
    }

    // cost = -(log2(W) + S) * ln2  (panel 1, lane 63, last quad)
    if (q == NPAN - 1 && t == 63)
        out[b] = -(flog2(pW[KC - 1]) + (float)S) * LN2;
}

extern "C" void kernel_launch(void* const* d_in, const int* in_sizes, int n_in,
                              void* d_out, int out_size, void* d_ws, size_t ws_size,
                              hipStream_t stream) {
    const float* D = (const float*)d_in[0];
    float* out = (float*)d_out;
    const int B = in_sizes[0] / (N * N);

    unsigned long long* pay = (unsigned long long*)d_ws;
    const size_t payBytes = (size_t)B * NQ * 2 * sizeof(unsigned long long);

    // poison the mailbox each launch (graph-capturable async memset)
    hipMemsetAsync(d_ws, 0xFF, payBytes, stream);

    const int nJobs = B * NPAN;          // 128
    softdtw_kernel<<<nJobs / 8, TPB, 0, stream>>>(D, out, pay);
}

// Round 26
// 254.100 us; speedup vs baseline: 3.1117x; 3.1117x over previous
//
#include <hip/hip_runtime.h>

// Soft-DTW, gamma=1.0, B=64, N=M=1024. Linear-weight cells + integer-exponent
// scale tracking (R15-R20 numerics, proven absmax 0.0).
// R26 = R20 (best, 254us) with the inter-iteration shfl latency covered:
//  (1) the 5 __shfl_up handoffs are issued IMMEDIATELY after the masked
//      commit (exW/exS final), so producer-publish + D-loads + consumer
//      prefetch (~60 instrs) issue under the ~120cyc ds_bpermute latency
//      instead of the wave stalling on it at the next iteration top;
//  (2) no per-iteration sched_barrier(0) — compiler schedules freely,
//      plain loads keep compiler-tracked waitcnt precise.
// Everything else R20-verbatim: NPAN=2 panels (128 blocks), poison global
// mailbox (relaxed u64, self-validating), 8-deep static-indexed consumer
// prefetch ring, 2-slot plain-load D ring, frexp/ldexp integer renorm.

#define LOG2E 1.4426950408889634f
#define LN2  0.6931471805599453f

constexpr int N = 1024;
constexpr int TPB = 64;              // one wave per block
constexpr int KC = 8;                // columns per thread (panel = 512 cols)
constexpr int RQ = 4;                // rows per iteration (quad)
constexpr int NQ = N / RQ;           // 256 quads
constexpr int NPAN = 2;
constexpr int PC = N / NPAN;         // 512 columns per panel
constexpr int ITER = 320;            // last real iteration: 255 + 63 = 318
constexpr unsigned long long POISON = 0xFFFFFFFFFFFFFFFFull;

__device__ __forceinline__ float fexp2(float x){float r;asm("v_exp_f32 %0, %1":"=v"(r):"v"(x));return r;}
__device__ __forceinline__ float flog2(float x){float r;asm("v_log_f32 %0, %1":"=v"(r):"v"(x));return r;}
__device__ __forceinline__ int   ffrexpe(float x){int r;asm("v_frexp_exp_i32_f32 %0, %1":"=v"(r):"v"(x));return r;}
__device__ __forceinline__ float fldexp(float x, int e){float r;asm("v_ldexp_f32 %0, %1, %2":"=v"(r):"v"(x),"v"(e));return r;}

__device__ __forceinline__ unsigned long long packv(float a, float b){
    return ((unsigned long long)__float_as_uint(b) << 32) | __float_as_uint(a);
}
__device__ __forceinline__ unsigned long long ldrelax(const unsigned long long* p){
    return __hip_atomic_load(p, __ATOMIC_RELAXED, __HIP_MEMORY_SCOPE_AGENT);
}

__global__ __launch_bounds__(TPB, 1)
void softdtw_kernel(const float* __restrict__ D, float* __restrict__ out,
                    unsigned long long* __restrict__ pay){
    const int blk = blockIdx.x;
    const int b = blk & 63;              // batch
    const int q = blk >> 6;              // panel (0 or 1)
    const int t = threadIdx.x;
    const float* __restrict__ bp = D + (size_t)b * N * N + q * PC + t * KC;

    const bool isProd = (t == TPB - 1) && (q == 0);
    const bool isCons = (t == 0) && (q == 1);
    const size_t base = (size_t)b * NQ * 2;   // one boundary per batch

    float pW[KC] = {0,0,0,0,0,0,0,0};
    int   S = 0;                          // scale: W_true = W * 2^S
    float luW = (t == 0 && q == 0) ? 1.0f : 0.0f;
    float exW[RQ] = {0,0,0,0};
    int   exS = 0;
    float nW[RQ] = {0,0,0,0};
    int   nS = 0;

    // consumer prefetch ring: quad j served from slot j&7 (static indexing)
    unsigned long long rg[8][2];
#pragma unroll
    for (int i = 0; i < 8; ++i) { rg[i][0] = POISON; rg[i][1] = POISON; }
    if (isCons) {
#pragma unroll
        for (int i = 0; i < 8; ++i) {
            rg[i][0] = ldrelax(&pay[base + (size_t)i * 2 + 0]);
            rg[i][1] = ldrelax(&pay[base + (size_t)i * 2 + 1]);
        }
    }

    float4 ld[2][RQ][2];                 // D ring: [slot][row][half], plain loads
#pragma unroll
    for (int x = 0; x < 2; ++x) {
        int pc = min(max(x - t, 0), NQ - 1);
        const float* a = bp + (size_t)(pc * RQ) * N;
#pragma unroll
        for (int r = 0; r < RQ; ++r) {
            ld[x][r][0] = *(const float4*)(a + (size_t)r * N);
            ld[x][r][1] = *(const float4*)(a + (size_t)r * N + 4);
        }
    }

    for (int jb = 0; jb < ITER; jb += 8) {
#pragma unroll
        for (int u = 0; u < 8; ++u) {
            const int p = jb + u - t;
            const bool active = (unsigned)p < (unsigned)NQ;
            const int slot = u & 1;

            // ---- consumer: validate + decode quad p (t=0 so p==jb+u, slot u) ----
            float cv0 = 0, cv1 = 0, cv2 = 0, cv3 = 0;
            if (isCons && active) {
                unsigned long long w0 = rg[u][0];
                unsigned long long w1 = rg[u][1];
                while (w0 == POISON) w0 = ldrelax(&pay[base + (size_t)p * 2 + 0]);
                while (w1 == POISON) w1 = ldrelax(&pay[base + (size_t)p * 2 + 1]);
                cv0 = __uint_as_float((unsigned)(w0 & 0xFFFFFFFFu));
                cv1 = __uint_as_float((unsigned)(w0 >> 32));
                cv2 = __uint_as_float((unsigned)(w1 & 0xFFFFFFFFu));
                cv3 = __uint_as_float((unsigned)(w1 >> 32));
            }

            // ---- anchor my scale at my first quad ----
            const int iS = nS;
            if (p == 0) {
                if (isCons) S = (int)(0.0f - cv0);
                else if (t == 0 && q == 0) S = 0;
                else S = iS;
            }

            // ---- incoming left edges in my scale ----
            float eW[RQ];
            {
                const int dS = iS - S;
                eW[0] = fldexp(nW[0], dS); eW[1] = fldexp(nW[1], dS);
                eW[2] = fldexp(nW[2], dS); eW[3] = fldexp(nW[3], dS);
            }
            if (t == 0 && q == 0) { eW[0] = eW[1] = eW[2] = eW[3] = 0.0f; }
            if (isCons) {
                const float Sf = (float)S;
                eW[0] = fexp2(0.0f - cv0 - Sf);
                eW[1] = fexp2(0.0f - cv1 - Sf);
                eW[2] = fexp2(0.0f - cv2 - Sf);
                eW[3] = fexp2(0.0f - cv3 - Sf);
            }

            // ---- 32 cells: W = f*(up + diag + left), 8-wide rows ----
            float a0 = pW[0], a1 = pW[1], a2 = pW[2], a3 = pW[3];
            float a4 = pW[4], a5 = pW[5], a6 = pW[6], a7 = pW[7];
            float dg = luW;
            float eR[RQ];
#pragma unroll
            for (int r = 0; r < RQ; ++r) {
                const float4 d0 = ld[slot][r][0];
                const float4 d1 = ld[slot][r][1];
                float f0 = fexp2(-LOG2E * d0.x), f1 = fexp2(-LOG2E * d0.y);
                float f2 = fexp2(-LOG2E * d0.z), f3 = fexp2(-LOG2E * d0.w);
                float f4 = fexp2(-LOG2E * d1.x), f5 = fexp2(-LOG2E * d1.y);
                float f6 = fexp2(-LOG2E * d1.z), f7 = fexp2(-LOG2E * d1.w);
                float s01 = a0 + a1, s12 = a1 + a2, s23 = a2 + a3, s34 = a3 + a4;
                float s45 = a4 + a5, s56 = a5 + a6, s67 = a6 + a7;
                float t0 = dg + eW[r];
                float W0 = f0 * (a0 + t0);
                float W1 = f1 * (s01 + W0);
                float W2 = f2 * (s12 + W1);
                float W3 = f3 * (s23 + W2);
                float W4 = f4 * (s34 + W3);
                float W5 = f5 * (s45 + W4);
                float W6 = f6 * (s56 + W5);
                float W7 = f7 * (s67 + W6);
                eR[r] = W7;
                dg = eW[r];
                a0 = W0; a1 = W1; a2 = W2; a3 = W3;
                a4 = W4; a5 = W5; a6 = W6; a7 = W7;
            }

            const int e = ffrexpe(a7);
            const float sc = fldexp(1.0f, -e);

            if (active) {                  // masked commit
                pW[0] = a0 * sc; pW[1] = a1 * sc; pW[2] = a2 * sc; pW[3] = a3 * sc;
                pW[4] = a4 * sc; pW[5] = a5 * sc; pW[6] = a6 * sc; pW[7] = a7 * sc;
                luW = dg * sc;
                exW[0] = eR[0] * sc; exW[1] = eR[1] * sc;
                exW[2] = eR[2] * sc; exW[3] = eR[3] * sc;
                S += e; exS = S;
            }

            // ---- EARLY pipelined handoff: issue shfls NOW so the publish /
            //      load / prefetch segments below cover the bpermute latency
            nW[0] = __shfl_up(exW[0], 1);
            nW[1] = __shfl_up(exW[1], 1);
            nW[2] = __shfl_up(exW[2], 1);
            nW[3] = __shfl_up(exW[3], 1);
            nS    = __shfl_up(exS, 1);

            // ---- producer: publish quad p (normalized v-form, relaxed u64) ----
            if (isProd && active) {
                const float Sf = (float)S;
                float v0 = 0.0f - (flog2(exW[0]) + Sf);
                float v1 = 0.0f - (flog2(exW[1]) + Sf);
                float v2 = 0.0f - (flog2(exW[2]) + Sf);
                float v3 = 0.0f - (flog2(exW[3]) + Sf);
                __hip_atomic_store(&pay[base + (size_t)p * 2 + 0], packv(v0, v1), __ATOMIC_RELAXED, __HIP_MEMORY_SCOPE_AGENT);
                __hip_atomic_store(&pay[base + (size_t)p * 2 + 1], packv(v2, v3), __ATOMIC_RELAXED, __HIP_MEMORY_SCOPE_AGENT);
            }

            // ---- D loads for iteration j+2 into the consumed slot ----
            {
                int pc = min(max(p + 2, 0), NQ - 1);
                const float* a = bp + (size_t)(pc * RQ) * N;
#pragma unroll
                for (int r = 0; r < RQ; ++r) {
                    ld[slot][r][0] = *(const float4*)(a + (size_t)r * N);
                    ld[slot][r][1] = *(const float4*)(a + (size_t)r * N + 4);
                }
            }

            // ---- consumer: prefetch quad p+8 into ring slot u (used at j+8) ----
            if (isCons && (p + 8) < NQ) {
                rg[u][0] = ldrelax(&pay[base + (size_t)(p + 8) * 2 + 0]);
                rg[u][1] = ldrelax(&pay[base + (size_t)(p + 8) * 2 + 1]);
            }
        }
    }

    // cost = -(log2(W) + S) * ln2  (panel 1, thread 63, last quad)
    if (q == NPAN - 1 && t == TPB - 1)
        out[b] = -(flog2(pW[KC - 1]) + (float)S) * LN2;
}

extern "C" void kernel_launch(void* const* d_in, const int* in_sizes, int n_in,
                              void* d_out, int out_size, void* d_ws, size_t ws_size,
                              hipStream_t stream) {
    const float* D = (const float*)d_in[0];
    float* out = (float*)d_out;
    const int B = in_sizes[0] / (N * N);

    unsigned long long* pay = (unsigned long long*)d_ws;
    const size_t payBytes = (size_t)B * NQ * 2 * sizeof(unsigned long long);

    // poison the mailbox each launch (graph-capturable async memset)
    hipMemsetAsync(d_ws, 0xFF, payBytes, stream);

    softdtw_kernel<<<B * NPAN, TPB, 0, stream>>>(D, out, pay);
}